// Round 12
// baseline (90.324 us; speedup 1.0000x reference)
//
#include <hip/hip_runtime.h>
#include <math.h>

namespace {

constexpr int NL  = 100;
constexpr int NT  = 20;
constexpr int NDV = 100;
constexpr float KEPS = 1e-8f;

struct Ptrs {
  const int*   user;
  const float* hist_lda;
  const float* hist_vector;
  const float* hist_info;
  const float* hist_authority;
  const float* hist_participants;
  const float* hist_interact;
  const float* timeDelta;
  const float* item_lda;
  const float* item_vector;
  const float* item_info;
  const float* item_authority;
  const float* item_participants;
  const float* item_interact;
  const float* know_lda_pref;
  const float* know_vector_pref;
  const float* lda_gain_ref;
  const float* com_participant_pref;
  const float* td_g;        const float* td_u;
  const float* info_part_g; const float* info_part_u;
  const float* topic_g;     const float* topic_u;
  const float* content_g;   const float* content_u;
  const float* info_w_u;
  const float* inter_apart_g; const float* inter_apart_u;
  const float* auth_apart_g;  const float* auth_apart_u;
  const float* part_w_g;    const float* part_w_u;
  const float* inter_w_g;   const float* inter_w_u;
  const float* auth_w_g;    const float* auth_w_u;
  const float* xref_g;      const float* xref_u;
  const float* xlam_g;      const float* xlam_u;
  const float* xalpha_g;    const float* xalpha_u;
  const float* xbeta_g;     const float* xbeta_u;
  const float* fc1_w; const float* fc1_b;
  const float* fc2_w; const float* fc2_b;
};

// One butterfly level as a VALU DPP add (no LDS pipe). CTRL is the DPP control.
template <int CTRL>
__device__ __forceinline__ float dppsum(float x) {
  int y = __builtin_amdgcn_update_dpp(0, __float_as_int(x), CTRL, 0xF, 0xF, true);
  return x + __int_as_float(y);
}
// Full 32-lane sum: result valid in lanes 16..31 of each 32-lane half-wave.
__device__ __forceinline__ float dpp_reduce32(float x) {
  x = dppsum<0xB1>(x);    // quad_perm [1,0,3,2]  : pair xor1
  x = dppsum<0x4E>(x);    // quad_perm [2,3,0,1]  : pair xor2
  x = dppsum<0x141>(x);   // row_half_mirror      : pair 4-groups
  x = dppsum<0x140>(x);   // row_mirror           : pair 8-groups
  x = dppsum<0x142>(x);   // row_bcast15          : row r 16-sum -> row r+1
  return x;               // lanes 16..31 (mod 32) hold the 32-lane total
}

// sc[] layout: 0 topic_w, 1 content_w, 2 info_w, 3 part_w, 4 inter_w, 5 auth_w,
//              6 xref, 7 lam, 8 alpha, 9 beta, 10 tdc,
//              11..13 info coef, 14..15 inter coef, 16..18 auth coef
__global__ __launch_bounds__(256, 6)   // occupancy-tier probe: cap VGPR for 6 blocks/CU
void fused_fwd(Ptrs p, float* __restrict__ out)
{
  const int b   = blockIdx.x;
  const int tid = threadIdx.x;

  __shared__ __align__(16) float lda_s [101 * NT];
  __shared__ __align__(16) float part_s[101 * NT];
  __shared__ __align__(16) float info_s [304];
  __shared__ __align__(16) float auth_s [304];
  __shared__ __align__(16) float inter_s[202];
  __shared__ __align__(16) float td_s   [100];
  __shared__ __align__(16) float u_lda[NT], u_part[NT], gref[NT];
  __shared__ float dotv_s[101], nnv_s[101];
  __shared__ float sc[19];
  __shared__ float norm1;
  __shared__ float gw_s[NL];
  __shared__ float cg_s;
  __shared__ float partial_s[12][NT];
  __shared__ float feat_s[3 * NT];

  const int u = p.user[b];
  const float4 fz = make_float4(0.f, 0.f, 0.f, 0.f);

  const int c      = tid & 31;   // lane in half-wave
  const int rowoff = tid >> 5;   // 0..7
  const int w      = tid >> 6;   // wave id 0..3
  const int l64    = tid & 63;   // lane in wave

  // ============ 1) ISSUE async global->LDS staging for ALL hist arrays ============
  // HW semantics: LDS dest = wave-uniform base + lane*16. Every issue has active
  // lanes starting at lane 0 of its wave (verified m97 pattern).
  {
    const float* hl = p.hist_lda          + (size_t)b * NL * NT;
    const float* hq = p.hist_participants + (size_t)b * NL * NT;
    __builtin_amdgcn_global_load_lds(hl + (size_t)tid * 4, &lda_s [tid * 4], 16, 0, 0);
    __builtin_amdgcn_global_load_lds(hq + (size_t)tid * 4, &part_s[tid * 4], 16, 0, 0);
    if (tid < 244) {   // waves 0-2 full, wave 3 lanes 0..51 (lane-0-aligned)
      __builtin_amdgcn_global_load_lds(hl + (size_t)(256 + tid) * 4, &lda_s [(256 + tid) * 4], 16, 0, 0);
      __builtin_amdgcn_global_load_lds(hq + (size_t)(256 + tid) * 4, &part_s[(256 + tid) * 4], 16, 0, 0);
    }
    const float* hi = p.hist_info      + (size_t)b * 300;
    const float* ha = p.hist_authority + (size_t)b * 300;
    const float* hn = p.hist_interact  + (size_t)b * 200;
    const float* ht = p.timeDelta      + (size_t)b * 100;
    if (w == 0) {                       // info: 75 float4
      __builtin_amdgcn_global_load_lds(hi + (size_t)l64 * 4, &info_s[l64 * 4], 16, 0, 0);
      if (l64 < 11)
        __builtin_amdgcn_global_load_lds(hi + (size_t)(64 + l64) * 4, &info_s[(64 + l64) * 4], 16, 0, 0);
    } else if (w == 1) {                // authority: 75 float4
      __builtin_amdgcn_global_load_lds(ha + (size_t)l64 * 4, &auth_s[l64 * 4], 16, 0, 0);
      if (l64 < 11)
        __builtin_amdgcn_global_load_lds(ha + (size_t)(64 + l64) * 4, &auth_s[(64 + l64) * 4], 16, 0, 0);
    } else if (w == 2) {                // interact: 50 float4
      if (l64 < 50)
        __builtin_amdgcn_global_load_lds(hn + (size_t)l64 * 4, &inter_s[l64 * 4], 16, 0, 0);
    } else {                            // timeDelta: 25 float4
      if (l64 < 25)
        __builtin_amdgcn_global_load_lds(ht + (size_t)l64 * 4, &td_s[l64 * 4], 16, 0, 0);
    }
  }

  // ============ 2) ISSUE phase-A vector loads (13 float4 / thread) ============
  const float4* hv4 = (const float4*)(p.hist_vector + (size_t)b * NL * NDV);
  const float4* iv4 = (const float4*)(p.item_vector + (size_t)b * NDV);
  float4 uv = fz;
  if (c < 25) uv = ((const float4*)(p.know_vector_pref + (size_t)u * NDV))[c];
  float4 av[13];
  #pragma unroll
  for (int i = 0; i < 13; ++i) {
    const int r = i * 8 + rowoff;
    av[i] = fz;
    if (c < 25 && r <= 100) av[i] = (r < NL) ? hv4[r * 25 + c] : iv4[c];
  }

  // ============ 3) ISSUE tiny reg-staged loads (item/user rows + scalars) ============
  float4 xf = fz;
  if      (tid < 5)  xf = ((const float4*)(p.item_lda          + (size_t)b * NT))[tid];
  else if (tid < 10) xf = ((const float4*)(p.item_participants + (size_t)b * NT))[tid - 5];
  else if (tid < 15) xf = ((const float4*)(p.know_lda_pref        + (size_t)u * NT))[tid - 10];
  else if (tid < 20) xf = ((const float4*)(p.com_participant_pref + (size_t)u * NT))[tid - 15];
  else if (tid < 25) xf = ((const float4*)(p.lda_gain_ref         + (size_t)u * NT))[tid - 20];
  float e0 = 0.f, e1 = 0.f, e2 = 0.f;
  if      (tid == 250) { e0 = p.item_info[(size_t)b*3];      e1 = p.item_info[(size_t)b*3+1];      e2 = p.item_info[(size_t)b*3+2]; }
  else if (tid == 251) { e0 = p.item_authority[(size_t)b*3]; e1 = p.item_authority[(size_t)b*3+1]; e2 = p.item_authority[(size_t)b*3+2]; }
  else if (tid == 252) { e0 = p.item_interact[(size_t)b*2];  e1 = p.item_interact[(size_t)b*2+1]; }

  // ============ 4) ISSUE sc loads (19 lanes, branchless pointer selects) ============
  const int  k      = tid - 96;
  const bool has_sc = (k >= 0 && k < 19);
  float g0v = 0.f, u0v = 0.f;
  {
    const int kk = has_sc ? k : 0;
    const float* gp =
      kk==0 ? p.topic_g   : kk==1 ? p.content_g : kk==2 ? p.info_w_u :
      kk==3 ? p.part_w_g  : kk==4 ? p.inter_w_g : kk==5 ? p.auth_w_g :
      kk==6 ? p.xref_g    : kk==7 ? p.xlam_g    : kk==8 ? p.xalpha_g :
      kk==9 ? p.xbeta_g   : kk==10? p.td_g      :
      kk<=13? p.info_part_g : kk<=15? p.inter_apart_g : p.auth_apart_g;
    const float* up =
      kk==0 ? p.topic_u   : kk==1 ? p.content_u : kk==2 ? p.info_w_u :
      kk==3 ? p.part_w_u  : kk==4 ? p.inter_w_u : kk==5 ? p.auth_w_u :
      kk==6 ? p.xref_u    : kk==7 ? p.xlam_u    : kk==8 ? p.xalpha_u :
      kk==9 ? p.xbeta_u   : kk==10? p.td_u      :
      kk<=13? p.info_part_u : kk<=15? p.inter_apart_u : p.auth_apart_u;
    const int go = kk<=10 ? 0 : kk<=13 ? kk-11 : kk<=15 ? kk-14 : kk-16;
    const int uo = kk<=10 ? u : kk<=13 ? u*3+kk-11 : kk<=15 ? u*2+kk-14 : u*3+kk-16;
    if (has_sc) { g0v = gp[go]; u0v = up[uo]; }
  }

  // ============ 5) LDS writes for the tiny reg-staged pieces ============
  if      (tid < 5)  ((float4*)lda_s) [500 + tid]      = xf;
  else if (tid < 10) ((float4*)part_s)[500 + tid - 5]  = xf;
  else if (tid < 15) ((float4*)u_lda) [tid - 10]       = xf;
  else if (tid < 20) ((float4*)u_part)[tid - 15]       = xf;
  else if (tid < 25) ((float4*)gref)  [tid - 20]       = xf;
  if      (tid == 250) { info_s[300] = e0; info_s[301] = e1; info_s[302] = e2; }
  else if (tid == 251) { auth_s[300] = e0; auth_s[301] = e1; auth_s[302] = e2; }
  else if (tid == 252) { inter_s[200] = e0; inter_s[201] = e1; }

  if (has_sc) sc[k] = g0v + u0v;

  // ============ 6) phase-A reduce (DPP, zero DS-pipe) + dotv/nnv to LDS ============
  #pragma unroll
  for (int i = 0; i < 13; ++i) {
    const int r = i * 8 + rowoff;
    float d = uv.x*av[i].x + uv.y*av[i].y + uv.z*av[i].z + uv.w*av[i].w;
    float n = av[i].x*av[i].x + av[i].y*av[i].y + av[i].z*av[i].z + av[i].w*av[i].w;
    d = dpp_reduce32(d);
    n = dpp_reduce32(n);
    if (c == 16 && r <= 100) { dotv_s[r] = d; nnv_s[r] = n; }
  }
  if (tid < 32) {   // ||know_vector_pref[u]||, total lands in lanes 16..31
    float s = uv.x*uv.x + uv.y*uv.y + uv.z*uv.z + uv.w*uv.w;
    s = dpp_reduce32(s);
    if (tid == 16) norm1 = sqrtf(s);
  }

  __syncthreads();   // ONLY front-end barrier: drains gload_lds (vmcnt) + ds writes

  // ============ PHASE B: per-row gains (rows 0..99 hist, 100 item) ============
  if (tid <= 100) {
    const int l = tid;
    const float4* lr4 = (const float4*)&lda_s [l * NT];
    const float4* pr4 = (const float4*)&part_s[l * NT];
    float dot_l = 0.f, nn_l = 0.f, dot_p = 0.f, nn_p = 0.f;
    float nu_l = 0.f, nu_p = 0.f;   // pref-vector norms, inline
    #pragma unroll
    for (int i = 0; i < 5; ++i) {
      float4 a = lr4[i];
      float4 q = pr4[i];
      float ul0 = u_lda[4*i+0], ul1 = u_lda[4*i+1], ul2 = u_lda[4*i+2], ul3 = u_lda[4*i+3];
      float up0 = u_part[4*i+0], up1 = u_part[4*i+1], up2 = u_part[4*i+2], up3 = u_part[4*i+3];
      dot_l += ul0*a.x + ul1*a.y + ul2*a.z + ul3*a.w;
      nn_l  += a.x*a.x + a.y*a.y + a.z*a.z + a.w*a.w;
      nu_l  += ul0*ul0 + ul1*ul1 + ul2*ul2 + ul3*ul3;
      dot_p += up0*q.x + up1*q.y + up2*q.z + up3*q.w;
      nn_p  += q.x*q.x + q.y*q.y + q.z*q.z + q.w*q.w;
      nu_p  += up0*up0 + up1*up1 + up2*up2 + up3*up3;
    }
    // hardware-rate rcp instead of exact f32 division (tolerance headroom ~50x)
    float lda_gain = dot_l * __builtin_amdgcn_rcpf(fmaxf(sqrtf(nu_l) * sqrtf(nn_l), KEPS));
    float part_sim = dot_p * __builtin_amdgcn_rcpf(fmaxf(sqrtf(nu_p) * sqrtf(nn_p), KEPS));
    float vec_gain = dotv_s[l] * __builtin_amdgcn_rcpf(fmaxf(norm1 * sqrtf(nnv_s[l]), KEPS));
    float info_gain  = sc[11]*info_s[l*3+0] + sc[12]*info_s[l*3+1] + sc[13]*info_s[l*3+2];
    float inter_gain = sc[14]*inter_s[l*2+0] + sc[15]*inter_s[l*2+1];
    float auth_gain  = sc[16]*auth_s[l*3+0] + sc[17]*auth_s[l*3+1] + sc[18]*auth_s[l*3+2];

    float x = lda_gain*sc[0] + vec_gain*sc[1] + info_gain*sc[2]
            + part_sim*sc[3] + inter_gain*sc[4] + auth_gain*sc[5]
            - sc[6];
    float xa  = fabsf(x);
    bool  pos = (x > 0.f);
    float v   = __powf(xa, pos ? sc[8] : sc[9]);   // exp2(e*log2(x)); __powf(0,e>0)=0
    float gg  = pos ? v : -sc[7] * v;
    if (l < NL) gw_s[l] = gg * __expf(-td_s[l] * sc[10]);
    else        cg_s   = gg;
  }
  __syncthreads();

  // ============ PHASE C: hist_topic partials, 12 groups x 20 ============
  if (tid < 240) {
    const int g = tid / NT, t = tid % NT;
    const int l0  = g * 8 + (g < 4 ? g : 4);
    const int cnt = 8 + (g < 4 ? 1 : 0);
    float acc = 0.f;
    for (int j = 0; j < cnt; ++j) acc += lda_s[(l0 + j) * NT + t] * gw_s[l0 + j];
    partial_s[g][t] = acc;
  }
  __syncthreads();

  // ============ PHASE D: features ============
  if (tid < NT) {
    float htop = 0.f;
    #pragma unroll
    for (int g = 0; g < 12; ++g) htop += partial_s[g][tid];
    float diff = gref[tid] - htop;
    float curr = cg_s * lda_s[100 * NT + tid];
    feat_s[tid]          = diff;
    feat_s[NT + tid]     = diff * curr;
    feat_s[2 * NT + tid] = curr;
  }
  __syncthreads();

  // ============ PHASE E: fc1 + fc2 ============
  if (tid < 32) {
    float hp = 0.f;
    if (tid < NT) {
      float acc = p.fc1_b[tid];
      const float* wrow = p.fc1_w + tid * 60;
      #pragma unroll
      for (int kk2 = 0; kk2 < 60; ++kk2) acc += wrow[kk2] * feat_s[kk2];
      hp = acc * p.fc2_w[tid];
    }
    #pragma unroll
    for (int m = 1; m < 32; m <<= 1) hp += __shfl_xor(hp, m);
    if (tid == 0) out[b] = hp + p.fc2_b[0];
  }
}

} // namespace

extern "C" void kernel_launch(void* const* d_in, const int* in_sizes, int n_in,
                              void* d_out, int out_size, void* d_ws, size_t ws_size,
                              hipStream_t stream) {
  Ptrs p;
  p.user              = (const int*)  d_in[0];
  p.hist_lda          = (const float*)d_in[1];
  p.hist_vector       = (const float*)d_in[2];
  p.hist_info         = (const float*)d_in[3];
  p.hist_authority    = (const float*)d_in[4];
  p.hist_participants = (const float*)d_in[5];
  p.hist_interact     = (const float*)d_in[6];
  p.timeDelta         = (const float*)d_in[7];
  p.item_lda          = (const float*)d_in[8];
  p.item_vector       = (const float*)d_in[9];
  p.item_info         = (const float*)d_in[10];
  p.item_authority    = (const float*)d_in[11];
  p.item_participants = (const float*)d_in[12];
  p.item_interact     = (const float*)d_in[13];
  p.know_lda_pref     = (const float*)d_in[14];
  p.know_vector_pref  = (const float*)d_in[15];
  p.lda_gain_ref      = (const float*)d_in[16];
  p.com_participant_pref = (const float*)d_in[17];
  p.td_g   = (const float*)d_in[18];  p.td_u   = (const float*)d_in[19];
  p.info_part_g = (const float*)d_in[20]; p.info_part_u = (const float*)d_in[21];
  p.topic_g   = (const float*)d_in[22]; p.topic_u   = (const float*)d_in[23];
  p.content_g = (const float*)d_in[24]; p.content_u = (const float*)d_in[25];
  p.info_w_u  = (const float*)d_in[26];
  p.inter_apart_g = (const float*)d_in[27]; p.inter_apart_u = (const float*)d_in[28];
  p.auth_apart_g  = (const float*)d_in[29]; p.auth_apart_u  = (const float*)d_in[30];
  p.part_w_g  = (const float*)d_in[31]; p.part_w_u  = (const float*)d_in[32];
  p.inter_w_g = (const float*)d_in[33]; p.inter_w_u = (const float*)d_in[34];
  p.auth_w_g  = (const float*)d_in[35]; p.auth_w_u  = (const float*)d_in[36];
  p.xref_g   = (const float*)d_in[37]; p.xref_u   = (const float*)d_in[38];
  p.xlam_g   = (const float*)d_in[39]; p.xlam_u   = (const float*)d_in[40];
  p.xalpha_g = (const float*)d_in[41]; p.xalpha_u = (const float*)d_in[42];
  p.xbeta_g  = (const float*)d_in[43]; p.xbeta_u  = (const float*)d_in[44];
  p.fc1_w = (const float*)d_in[45]; p.fc1_b = (const float*)d_in[46];
  p.fc2_w = (const float*)d_in[47]; p.fc2_b = (const float*)d_in[48];

  float* out = (float*)d_out;
  const int nblocks = in_sizes[0];  // B = 8192
  fused_fwd<<<nblocks, 256, 0, stream>>>(p, out);
}

// Round 13
// 88.999 us; speedup vs baseline: 1.0149x; 1.0149x over previous
//
#include <hip/hip_runtime.h>
#include <math.h>

namespace {

constexpr int NL  = 100;
constexpr int NT  = 20;
constexpr int NDV = 100;
constexpr float KEPS = 1e-8f;

struct Ptrs {
  const int*   user;
  const float* hist_lda;
  const float* hist_vector;
  const float* hist_info;
  const float* hist_authority;
  const float* hist_participants;
  const float* hist_interact;
  const float* timeDelta;
  const float* item_lda;
  const float* item_vector;
  const float* item_info;
  const float* item_authority;
  const float* item_participants;
  const float* item_interact;
  const float* know_lda_pref;
  const float* know_vector_pref;
  const float* lda_gain_ref;
  const float* com_participant_pref;
  const float* td_g;        const float* td_u;
  const float* info_part_g; const float* info_part_u;
  const float* topic_g;     const float* topic_u;
  const float* content_g;   const float* content_u;
  const float* info_w_u;
  const float* inter_apart_g; const float* inter_apart_u;
  const float* auth_apart_g;  const float* auth_apart_u;
  const float* part_w_g;    const float* part_w_u;
  const float* inter_w_g;   const float* inter_w_u;
  const float* auth_w_g;    const float* auth_w_u;
  const float* xref_g;      const float* xref_u;
  const float* xlam_g;      const float* xlam_u;
  const float* xalpha_g;    const float* xalpha_u;
  const float* xbeta_g;     const float* xbeta_u;
  const float* fc1_w; const float* fc1_b;
  const float* fc2_w; const float* fc2_b;
};

// One butterfly level as a VALU DPP add (no LDS pipe). CTRL is the DPP control.
template <int CTRL>
__device__ __forceinline__ float dppsum(float x) {
  int y = __builtin_amdgcn_update_dpp(0, __float_as_int(x), CTRL, 0xF, 0xF, true);
  return x + __int_as_float(y);
}
// Full 32-lane sum: result valid in lanes 16..31 of each 32-lane half-wave.
__device__ __forceinline__ float dpp_reduce32(float x) {
  x = dppsum<0xB1>(x);    // quad_perm [1,0,3,2]  : pair xor1
  x = dppsum<0x4E>(x);    // quad_perm [2,3,0,1]  : pair xor2
  x = dppsum<0x141>(x);   // row_half_mirror      : pair 4-groups
  x = dppsum<0x140>(x);   // row_mirror           : pair 8-groups
  x = dppsum<0x142>(x);   // row_bcast15          : row r 16-sum -> row r+1
  return x;               // lanes 16..31 (mod 32) hold the 32-lane total
}

// sc[] layout: 0 topic_w, 1 content_w, 2 info_w, 3 part_w, 4 inter_w, 5 auth_w,
//              6 xref, 7 lam, 8 alpha, 9 beta, 10 tdc,
//              11..13 info coef, 14..15 inter coef, 16..18 auth coef
__global__ __launch_bounds__(256)
void fused_fwd(Ptrs p, float* __restrict__ out)
{
  const int b   = blockIdx.x;
  const int tid = threadIdx.x;

  __shared__ __align__(16) float lda_s [101 * NT];
  __shared__ __align__(16) float part_s[101 * NT];
  __shared__ __align__(16) float info_s [304];
  __shared__ __align__(16) float auth_s [304];
  __shared__ __align__(16) float inter_s[202];
  __shared__ __align__(16) float td_s   [100];
  __shared__ __align__(16) float u_lda[NT], u_part[NT], gref[NT];
  __shared__ float dotv_s[101], nnv_s[101];
  __shared__ float sc[19];
  __shared__ float norm1;
  __shared__ float gw_s[NL];
  __shared__ float cg_s;
  __shared__ float partial_s[12][NT];
  __shared__ float feat_s[3 * NT];

  const int u = p.user[b];
  const float4 fz = make_float4(0.f, 0.f, 0.f, 0.f);

  const int c      = tid & 31;   // lane in half-wave
  const int rowoff = tid >> 5;   // 0..7
  const int w      = tid >> 6;   // wave id 0..3
  const int l64    = tid & 63;   // lane in wave

  // ============ 1) ISSUE async global->LDS staging for ALL hist arrays ============
  // HW semantics: LDS dest = wave-uniform base + lane*16. Every issue has active
  // lanes starting at lane 0 of its wave (verified m97 pattern).
  {
    const float* hl = p.hist_lda          + (size_t)b * NL * NT;
    const float* hq = p.hist_participants + (size_t)b * NL * NT;
    __builtin_amdgcn_global_load_lds(hl + (size_t)tid * 4, &lda_s [tid * 4], 16, 0, 0);
    __builtin_amdgcn_global_load_lds(hq + (size_t)tid * 4, &part_s[tid * 4], 16, 0, 0);
    if (tid < 244) {   // waves 0-2 full, wave 3 lanes 0..51 (lane-0-aligned)
      __builtin_amdgcn_global_load_lds(hl + (size_t)(256 + tid) * 4, &lda_s [(256 + tid) * 4], 16, 0, 0);
      __builtin_amdgcn_global_load_lds(hq + (size_t)(256 + tid) * 4, &part_s[(256 + tid) * 4], 16, 0, 0);
    }
    const float* hi = p.hist_info      + (size_t)b * 300;
    const float* ha = p.hist_authority + (size_t)b * 300;
    const float* hn = p.hist_interact  + (size_t)b * 200;
    const float* ht = p.timeDelta      + (size_t)b * 100;
    if (w == 0) {                       // info: 75 float4
      __builtin_amdgcn_global_load_lds(hi + (size_t)l64 * 4, &info_s[l64 * 4], 16, 0, 0);
      if (l64 < 11)
        __builtin_amdgcn_global_load_lds(hi + (size_t)(64 + l64) * 4, &info_s[(64 + l64) * 4], 16, 0, 0);
    } else if (w == 1) {                // authority: 75 float4
      __builtin_amdgcn_global_load_lds(ha + (size_t)l64 * 4, &auth_s[l64 * 4], 16, 0, 0);
      if (l64 < 11)
        __builtin_amdgcn_global_load_lds(ha + (size_t)(64 + l64) * 4, &auth_s[(64 + l64) * 4], 16, 0, 0);
    } else if (w == 2) {                // interact: 50 float4
      if (l64 < 50)
        __builtin_amdgcn_global_load_lds(hn + (size_t)l64 * 4, &inter_s[l64 * 4], 16, 0, 0);
    } else {                            // timeDelta: 25 float4
      if (l64 < 25)
        __builtin_amdgcn_global_load_lds(ht + (size_t)l64 * 4, &td_s[l64 * 4], 16, 0, 0);
    }
  }

  // ============ 2) ISSUE phase-A vector loads (13 float4 / thread) ============
  const float4* hv4 = (const float4*)(p.hist_vector + (size_t)b * NL * NDV);
  const float4* iv4 = (const float4*)(p.item_vector + (size_t)b * NDV);
  float4 uv = fz;
  if (c < 25) uv = ((const float4*)(p.know_vector_pref + (size_t)u * NDV))[c];
  float4 av[13];
  #pragma unroll
  for (int i = 0; i < 13; ++i) {
    const int r = i * 8 + rowoff;
    av[i] = fz;
    if (c < 25 && r <= 100) av[i] = (r < NL) ? hv4[r * 25 + c] : iv4[c];
  }

  // ============ 3) ISSUE tiny reg-staged loads (item/user rows + scalars) ============
  float4 xf = fz;
  if      (tid < 5)  xf = ((const float4*)(p.item_lda          + (size_t)b * NT))[tid];
  else if (tid < 10) xf = ((const float4*)(p.item_participants + (size_t)b * NT))[tid - 5];
  else if (tid < 15) xf = ((const float4*)(p.know_lda_pref        + (size_t)u * NT))[tid - 10];
  else if (tid < 20) xf = ((const float4*)(p.com_participant_pref + (size_t)u * NT))[tid - 15];
  else if (tid < 25) xf = ((const float4*)(p.lda_gain_ref         + (size_t)u * NT))[tid - 20];
  float e0 = 0.f, e1 = 0.f, e2 = 0.f;
  if      (tid == 250) { e0 = p.item_info[(size_t)b*3];      e1 = p.item_info[(size_t)b*3+1];      e2 = p.item_info[(size_t)b*3+2]; }
  else if (tid == 251) { e0 = p.item_authority[(size_t)b*3]; e1 = p.item_authority[(size_t)b*3+1]; e2 = p.item_authority[(size_t)b*3+2]; }
  else if (tid == 252) { e0 = p.item_interact[(size_t)b*2];  e1 = p.item_interact[(size_t)b*2+1]; }

  // ============ 4) ISSUE sc loads (19 lanes, branchless pointer selects) ============
  const int  k      = tid - 96;
  const bool has_sc = (k >= 0 && k < 19);
  float g0v = 0.f, u0v = 0.f;
  {
    const int kk = has_sc ? k : 0;
    const float* gp =
      kk==0 ? p.topic_g   : kk==1 ? p.content_g : kk==2 ? p.info_w_u :
      kk==3 ? p.part_w_g  : kk==4 ? p.inter_w_g : kk==5 ? p.auth_w_g :
      kk==6 ? p.xref_g    : kk==7 ? p.xlam_g    : kk==8 ? p.xalpha_g :
      kk==9 ? p.xbeta_g   : kk==10? p.td_g      :
      kk<=13? p.info_part_g : kk<=15? p.inter_apart_g : p.auth_apart_g;
    const float* up =
      kk==0 ? p.topic_u   : kk==1 ? p.content_u : kk==2 ? p.info_w_u :
      kk==3 ? p.part_w_u  : kk==4 ? p.inter_w_u : kk==5 ? p.auth_w_u :
      kk==6 ? p.xref_u    : kk==7 ? p.xlam_u    : kk==8 ? p.xalpha_u :
      kk==9 ? p.xbeta_u   : kk==10? p.td_u      :
      kk<=13? p.info_part_u : kk<=15? p.inter_apart_u : p.auth_apart_u;
    const int go = kk<=10 ? 0 : kk<=13 ? kk-11 : kk<=15 ? kk-14 : kk-16;
    const int uo = kk<=10 ? u : kk<=13 ? u*3+kk-11 : kk<=15 ? u*2+kk-14 : u*3+kk-16;
    if (has_sc) { g0v = gp[go]; u0v = up[uo]; }
  }

  // ============ 5) LDS writes for the tiny reg-staged pieces ============
  if      (tid < 5)  ((float4*)lda_s) [500 + tid]      = xf;
  else if (tid < 10) ((float4*)part_s)[500 + tid - 5]  = xf;
  else if (tid < 15) ((float4*)u_lda) [tid - 10]       = xf;
  else if (tid < 20) ((float4*)u_part)[tid - 15]       = xf;
  else if (tid < 25) ((float4*)gref)  [tid - 20]       = xf;
  if      (tid == 250) { info_s[300] = e0; info_s[301] = e1; info_s[302] = e2; }
  else if (tid == 251) { auth_s[300] = e0; auth_s[301] = e1; auth_s[302] = e2; }
  else if (tid == 252) { inter_s[200] = e0; inter_s[201] = e1; }

  if (has_sc) sc[k] = g0v + u0v;

  // ============ 6) phase-A reduce (DPP, zero DS-pipe) + dotv/nnv to LDS ============
  #pragma unroll
  for (int i = 0; i < 13; ++i) {
    const int r = i * 8 + rowoff;
    float d = uv.x*av[i].x + uv.y*av[i].y + uv.z*av[i].z + uv.w*av[i].w;
    float n = av[i].x*av[i].x + av[i].y*av[i].y + av[i].z*av[i].z + av[i].w*av[i].w;
    d = dpp_reduce32(d);
    n = dpp_reduce32(n);
    if (c == 16 && r <= 100) { dotv_s[r] = d; nnv_s[r] = n; }
  }
  if (tid < 32) {   // ||know_vector_pref[u]||, total lands in lanes 16..31
    float s = uv.x*uv.x + uv.y*uv.y + uv.z*uv.z + uv.w*uv.w;
    s = dpp_reduce32(s);
    if (tid == 16) norm1 = sqrtf(s);
  }

  __syncthreads();   // ONLY front-end barrier: drains gload_lds (vmcnt) + ds writes

  // ============ PHASE B: per-row gains (rows 0..99 hist, 100 item) ============
  if (tid <= 100) {
    const int l = tid;
    const float4* lr4 = (const float4*)&lda_s [l * NT];
    const float4* pr4 = (const float4*)&part_s[l * NT];
    float dot_l = 0.f, nn_l = 0.f, dot_p = 0.f, nn_p = 0.f;
    float nu_l = 0.f, nu_p = 0.f;   // pref-vector norms, inline
    #pragma unroll
    for (int i = 0; i < 5; ++i) {
      float4 a = lr4[i];
      float4 q = pr4[i];
      float ul0 = u_lda[4*i+0], ul1 = u_lda[4*i+1], ul2 = u_lda[4*i+2], ul3 = u_lda[4*i+3];
      float up0 = u_part[4*i+0], up1 = u_part[4*i+1], up2 = u_part[4*i+2], up3 = u_part[4*i+3];
      dot_l += ul0*a.x + ul1*a.y + ul2*a.z + ul3*a.w;
      nn_l  += a.x*a.x + a.y*a.y + a.z*a.z + a.w*a.w;
      nu_l  += ul0*ul0 + ul1*ul1 + ul2*ul2 + ul3*ul3;
      dot_p += up0*q.x + up1*q.y + up2*q.z + up3*q.w;
      nn_p  += q.x*q.x + q.y*q.y + q.z*q.z + q.w*q.w;
      nu_p  += up0*up0 + up1*up1 + up2*up2 + up3*up3;
    }
    // hardware-rate rcp instead of exact f32 division (tolerance headroom ~50x)
    float lda_gain = dot_l * __builtin_amdgcn_rcpf(fmaxf(sqrtf(nu_l) * sqrtf(nn_l), KEPS));
    float part_sim = dot_p * __builtin_amdgcn_rcpf(fmaxf(sqrtf(nu_p) * sqrtf(nn_p), KEPS));
    float vec_gain = dotv_s[l] * __builtin_amdgcn_rcpf(fmaxf(norm1 * sqrtf(nnv_s[l]), KEPS));
    float info_gain  = sc[11]*info_s[l*3+0] + sc[12]*info_s[l*3+1] + sc[13]*info_s[l*3+2];
    float inter_gain = sc[14]*inter_s[l*2+0] + sc[15]*inter_s[l*2+1];
    float auth_gain  = sc[16]*auth_s[l*3+0] + sc[17]*auth_s[l*3+1] + sc[18]*auth_s[l*3+2];

    float x = lda_gain*sc[0] + vec_gain*sc[1] + info_gain*sc[2]
            + part_sim*sc[3] + inter_gain*sc[4] + auth_gain*sc[5]
            - sc[6];
    float xa  = fabsf(x);
    bool  pos = (x > 0.f);
    float v   = __powf(xa, pos ? sc[8] : sc[9]);   // exp2(e*log2(x)); __powf(0,e>0)=0
    float gg  = pos ? v : -sc[7] * v;
    if (l < NL) gw_s[l] = gg * __expf(-td_s[l] * sc[10]);
    else        cg_s   = gg;
  }
  __syncthreads();

  // ============ PHASE C: hist_topic partials, 12 groups x 20 ============
  if (tid < 240) {
    const int g = tid / NT, t = tid % NT;
    const int l0  = g * 8 + (g < 4 ? g : 4);
    const int cnt = 8 + (g < 4 ? 1 : 0);
    float acc = 0.f;
    for (int j = 0; j < cnt; ++j) acc += lda_s[(l0 + j) * NT + t] * gw_s[l0 + j];
    partial_s[g][t] = acc;
  }
  __syncthreads();

  // ============ PHASE D: features ============
  if (tid < NT) {
    float htop = 0.f;
    #pragma unroll
    for (int g = 0; g < 12; ++g) htop += partial_s[g][tid];
    float diff = gref[tid] - htop;
    float curr = cg_s * lda_s[100 * NT + tid];
    feat_s[tid]          = diff;
    feat_s[NT + tid]     = diff * curr;
    feat_s[2 * NT + tid] = curr;
  }
  __syncthreads();

  // ============ PHASE E: fc1 + fc2 ============
  if (tid < 32) {
    float hp = 0.f;
    if (tid < NT) {
      float acc = p.fc1_b[tid];
      const float* wrow = p.fc1_w + tid * 60;
      #pragma unroll
      for (int kk2 = 0; kk2 < 60; ++kk2) acc += wrow[kk2] * feat_s[kk2];
      hp = acc * p.fc2_w[tid];
    }
    #pragma unroll
    for (int m = 1; m < 32; m <<= 1) hp += __shfl_xor(hp, m);
    if (tid == 0) out[b] = hp + p.fc2_b[0];
  }
}

} // namespace

extern "C" void kernel_launch(void* const* d_in, const int* in_sizes, int n_in,
                              void* d_out, int out_size, void* d_ws, size_t ws_size,
                              hipStream_t stream) {
  Ptrs p;
  p.user              = (const int*)  d_in[0];
  p.hist_lda          = (const float*)d_in[1];
  p.hist_vector       = (const float*)d_in[2];
  p.hist_info         = (const float*)d_in[3];
  p.hist_authority    = (const float*)d_in[4];
  p.hist_participants = (const float*)d_in[5];
  p.hist_interact     = (const float*)d_in[6];
  p.timeDelta         = (const float*)d_in[7];
  p.item_lda          = (const float*)d_in[8];
  p.item_vector       = (const float*)d_in[9];
  p.item_info         = (const float*)d_in[10];
  p.item_authority    = (const float*)d_in[11];
  p.item_participants = (const float*)d_in[12];
  p.item_interact     = (const float*)d_in[13];
  p.know_lda_pref     = (const float*)d_in[14];
  p.know_vector_pref  = (const float*)d_in[15];
  p.lda_gain_ref      = (const float*)d_in[16];
  p.com_participant_pref = (const float*)d_in[17];
  p.td_g   = (const float*)d_in[18];  p.td_u   = (const float*)d_in[19];
  p.info_part_g = (const float*)d_in[20]; p.info_part_u = (const float*)d_in[21];
  p.topic_g   = (const float*)d_in[22]; p.topic_u   = (const float*)d_in[23];
  p.content_g = (const float*)d_in[24]; p.content_u = (const float*)d_in[25];
  p.info_w_u  = (const float*)d_in[26];
  p.inter_apart_g = (const float*)d_in[27]; p.inter_apart_u = (const float*)d_in[28];
  p.auth_apart_g  = (const float*)d_in[29]; p.auth_apart_u  = (const float*)d_in[30];
  p.part_w_g  = (const float*)d_in[31]; p.part_w_u  = (const float*)d_in[32];
  p.inter_w_g = (const float*)d_in[33]; p.inter_w_u = (const float*)d_in[34];
  p.auth_w_g  = (const float*)d_in[35]; p.auth_w_u  = (const float*)d_in[36];
  p.xref_g   = (const float*)d_in[37]; p.xref_u   = (const float*)d_in[38];
  p.xlam_g   = (const float*)d_in[39]; p.xlam_u   = (const float*)d_in[40];
  p.xalpha_g = (const float*)d_in[41]; p.xalpha_u = (const float*)d_in[42];
  p.xbeta_g  = (const float*)d_in[43]; p.xbeta_u  = (const float*)d_in[44];
  p.fc1_w = (const float*)d_in[45]; p.fc1_b = (const float*)d_in[46];
  p.fc2_w = (const float*)d_in[47]; p.fc2_b = (const float*)d_in[48];

  float* out = (float*)d_out;
  const int nblocks = in_sizes[0];  // B = 8192
  fused_fwd<<<nblocks, 256, 0, stream>>>(p, out);
}